// Round 3
// baseline (262.575 us; speedup 1.0000x reference)
//
#include <hip/hip_runtime.h>
#include <hip/hip_bf16.h>

// Gram matrix: G = X @ X^T, X = [512, 65536] fp32, out = [512, 512] fp32.
// Round 13: r12's counted-vmcnt dbuf REGRESSED (100->117us, Occ 24.9->17.4)
// -> the loop is NOT exposed-latency bound; 2 blocks/CU already overlap.
// Revised theory: r1 (non-symmetric) delivered 7.9 TB/s logical; symmetric
// variants sit at 5.1 TB/s -- we are duty-cycle/intensity-limited, and the
// fix that helps under BOTH theories is a BIGGER TILE (m93 ladder step):
//   - 256x256 output tiles: logical staging 512 MB -> 268 MB (rows read
//     1024x65536x4 instead of 2048x), MFMA per staged byte DOUBLES.
//   - 512 threads, 8 waves (2x4), per-wave 128x64 out: acc[8][4] f32x4 =
//     128 VGPR (m201-proven shape). B-fragments cvt'd on the fly so live
//     set stays ~170 VGPR.
//   - loop skeleton = r11's proven one (gload_lds + both-sides XOR swizzle
//     + plain __syncthreads pair, single-buffered 64 KB LDS). NO raw-barrier
//     pipeline (r12 lesson).
//   - grid 256 (1 block/CU): diag tiles (0,0),(1,1) x 64 chunks KC=1024
//     (32 iters) + off-diag (0,1) x 128 chunks KC=512 (16 iters); every
//     block stages exactly 1 MB. Atomics 10.5M -> 16.8M (+~8-17us, r6
//     scaling) -- paid for by halved traffic.
// History: r1 fused 135us (7.9 TB/s); r10 symmetric 100; r11 async-stage
// 100; r12 dbuf 117 (REVERTED).

typedef short bf16x8 __attribute__((ext_vector_type(8)));   // 8 bf16 = 4 VGPRs
typedef float f32x4  __attribute__((ext_vector_type(4)));   // MFMA acc

#define HW    65536
#define CDIM  512

__device__ __forceinline__ short f2bf(float f) {
    __hip_bfloat16 h = __float2bfloat16(f);   // RNE
    short s;
    __builtin_memcpy(&s, &h, sizeof(short));
    return s;
}

__device__ __forceinline__ bf16x8 cvt8(float4 a, float4 b) {
    bf16x8 v;
    v[0] = f2bf(a.x); v[1] = f2bf(a.y); v[2] = f2bf(a.z); v[3] = f2bf(a.w);
    v[4] = f2bf(b.x); v[5] = f2bf(b.y); v[6] = f2bf(b.z); v[7] = f2bf(b.w);
    return v;
}

// async global->LDS, 16 bytes per lane (dest = wave-uniform base + lane*16)
__device__ __forceinline__ void gload16(const float* g, float* l) {
    __builtin_amdgcn_global_load_lds(
        (const __attribute__((address_space(1))) void*)g,
        (__attribute__((address_space(3))) void*)l,
        16, 0, 0);
}

__global__ __launch_bounds__(512, 1)
void gram_kernel(const float* __restrict__ X, float* __restrict__ out) {
    // decode: p<128 -> diag tile (p>>6 in {0,1}), chunk p&63, KC=1024, 32 it
    //         p>=128 -> off tile (0,1), chunk p-128 (0..127), KC=512, 16 it
    const int p = blockIdx.x;
    int ti, tj, kbase, iters;
    if (p < 128) {
        ti = tj = p >> 6;
        kbase = (p & 63) << 10;
        iters = 32;
    } else {
        ti = 0; tj = 1;
        kbase = (p - 128) << 9;
        iters = 16;
    }
    const bool diag = (ti == tj);

    // fp32 panels [256][32], linear (source-side swizzle), 64 KB total
    __shared__ float As[256 * 32];
    __shared__ float Bs[256 * 32];

    const int t    = threadIdx.x;       // 0..511
    const int wave = t >> 6;            // 0..7
    const int lane = t & 63;
    const int wm   = wave & 1;          // 2x4 wave grid, wave = 128x64 out
    const int wn   = wave >> 1;         // 0..3

    // --- staging: round r (0..3): row = r*64 + (t>>3), 16B slot = t&7 ---
    // LDS slot s holds global k-slot s ^ (row&7); row&7 == (t>>3)&7 (64|r*64).
    const int srow = t >> 3;                       // 0..63
    const int sswz = (t & 7) ^ (srow & 7);
    const float* ga = X + (size_t)(ti * 256 + srow) * HW + kbase + sswz * 4;
    const float* gb = X + (size_t)(tj * 256 + srow) * HW + kbase + sswz * 4;
    float* la = As + t * 4;                        // + r*2048 floats per round
    float* lb = Bs + t * 4;

    // --- fragment read offsets (float units). Second 16B half = off ^ 4
    // (slot^1), valid since slot*4 is 16B-granular and ra*32 has bit2=0. ---
    const int fm = lane & 15;
    const int kg = lane >> 4;           // k-group: slots 2kg, 2kg+1 (swizzled)
    int a_off[8], b_off[4];
#pragma unroll
    for (int i = 0; i < 8; ++i) {
        const int ra = wm * 128 + i * 16 + fm;
        a_off[i] = ra * 32 + (((2 * kg) ^ (ra & 7)) << 2);
    }
#pragma unroll
    for (int j = 0; j < 4; ++j) {
        const int rb = wn * 64 + j * 16 + fm;
        b_off[j] = rb * 32 + (((2 * kg) ^ (rb & 7)) << 2);
    }

    f32x4 acc[8][4];
#pragma unroll
    for (int i = 0; i < 8; ++i)
#pragma unroll
        for (int j = 0; j < 4; ++j)
            acc[i][j] = (f32x4){0.f, 0.f, 0.f, 0.f};

    for (int it = 0; it < iters; ++it) {
        // async stage: 4 gloads (A), +4 if off-diag (B); 16B per lane
#pragma unroll
        for (int r = 0; r < 4; ++r)
            gload16(ga + (size_t)r * 64 * HW, la + r * 2048);
        if (!diag) {
#pragma unroll
            for (int r = 0; r < 4; ++r)
                gload16(gb + (size_t)r * 64 * HW, lb + r * 2048);
        }
        __syncthreads();   // drains vmcnt(0): stage visible to all waves

        // A fragments first (32 regs), then B on the fly (cap live VGPRs)
        bf16x8 af[8];
#pragma unroll
        for (int i = 0; i < 8; ++i) {
            const float4 h0 = *(const float4*)(As + a_off[i]);
            const float4 h1 = *(const float4*)(As + (a_off[i] ^ 4));
            af[i] = cvt8(h0, h1);
        }
        const float* Bb = diag ? As : Bs;
#pragma unroll
        for (int j = 0; j < 4; ++j) {
            const float4 h0 = *(const float4*)(Bb + b_off[j]);
            const float4 h1 = *(const float4*)(Bb + (b_off[j] ^ 4));
            const bf16x8 bf = cvt8(h0, h1);
#pragma unroll
            for (int i = 0; i < 8; ++i)
                acc[i][j] = __builtin_amdgcn_mfma_f32_16x16x32_bf16(
                    af[i], bf, acc[i][j], 0, 0, 0);
        }

        __syncthreads();   // all reads done before next iteration's stage
        ga += 32;
        gb += 32;
    }

    // --- epilogue: row-major coalesced atomics (diag/upper tiles only) ---
    // C/D layout (verified m89/m91): col = lane&15, row = (lane>>4)*4 + reg
    const int orow0 = ti * 256 + wm * 128 + (lane >> 4) * 4;
    const int ocol0 = tj * 256 + wn * 64 + fm;
#pragma unroll
    for (int i = 0; i < 8; ++i)
#pragma unroll
        for (int j = 0; j < 4; ++j)
#pragma unroll
            for (int r = 0; r < 4; ++r)
                atomicAdd(out + (orow0 + i * 16 + r) * CDIM + ocol0 + j * 16,
                          acc[i][j][r]);
}

// ---------------- mirror: copy upper tiles transposed into lower ----------------
__global__ __launch_bounds__(256)
void mirror_kernel(float* __restrict__ out) {
    const int id = blockIdx.x * 256 + threadIdx.x;   // 0..262143
    const int r = id >> 9;
    const int c = id & 511;
    if ((r >> 8) > (c >> 8))          // 256-grain tiles now
        out[id] = out[c * CDIM + r];
}

extern "C" void kernel_launch(void* const* d_in, const int* in_sizes, int n_in,
                              void* d_out, int out_size, void* d_ws, size_t ws_size,
                              hipStream_t stream) {
    const float* x = (const float*)d_in[0];
    float* out = (float*)d_out;

    // zero the accumulator (harness poisons d_out with 0xAA before every launch)
    hipMemsetAsync(d_out, 0, (size_t)out_size * sizeof(float), stream);

    gram_kernel<<<dim3(256), dim3(512), 0, stream>>>(x, out);
    mirror_kernel<<<dim3(1024), dim3(256), 0, stream>>>(out);
}